// Round 6
// baseline (130.751 us; speedup 1.0000x reference)
//
#include <hip/hip_runtime.h>

// Morphological dilation: out[p,i,j] = max_{r,c}(xpad[p,i+r,j+c] + w[p,r,c]) + bias[p]
// p = plane (B*C=1024), H=W=128, 5x5, pad=2, stride=1, fp32. Zero pad participates.
// R6: no LDS, no barriers. Each thread owns a 4-col x 8-row strip; ALL 12 input
// rows (8 floats each) are loaded up-front into registers (36 independent VMEM
// in flight -> one progressive drain), then all 8 outputs computed from
// registers with static indexing. Latency hiding via ILP instead of per-row
// load-consume chains (R2/R3/R5 plateaued at 37-41 us on those).

static constexpr int H = 128, W = 128, KH = 5, KW = 5, PAD = 2;
static constexpr int RSTRIP = 8;            // output rows per thread
static constexpr int NROWS  = RSTRIP + KH - 1; // 12 input rows held in regs
static constexpr int RBAND  = 64;           // output rows per block (8 strips)
static constexpr int BANDS  = H / RBAND;    // 2 blocks per plane

#define MAX3(a, b, c) fmaxf(fmaxf((a), (b)), (c))

__global__ __launch_bounds__(256) void dilation_kernel(
    const float* __restrict__ x,
    const float* __restrict__ wgt,
    const float* __restrict__ bias,
    float* __restrict__ out)
{
    const int plane = blockIdx.x / BANDS;
    const int band  = blockIdx.x % BANDS;
    const int tid = threadIdx.x;
    const int cg  = tid & 31;     // column group: 4 cols each, 32 groups = 128 cols
    const int rs  = tid >> 5;     // row stream 0..7
    const int j0  = cg * 4;
    const int base = band * RBAND + rs * RSTRIP;

    const float* __restrict__ xp = x   + (size_t)plane * (H * W);
    float*       __restrict__ op = out + (size_t)plane * (H * W);
    const float* __restrict__ wp = wgt + plane * (KH * KW);

    // Plane-uniform weights -> SGPRs; bias applied last (exact ref op order).
    float wk[KH * KW];
#pragma unroll
    for (int i = 0; i < KH * KW; ++i) wk[i] = wp[i];
    const float bi = bias[plane];

    // Column-edge handling: window needs cols j0-2 .. j0+5 (8 floats).
    // L = float2 @ j0-2 (invalid for cg==0), M = float4 @ j0 (always valid),
    // R = float2 @ j0+4 (invalid for cg==31). Clamped addresses stay in-plane.
    const bool cgL = (cg > 0);
    const bool cgR = (cg < 31);
    const int colL = cgL ? (j0 - 2) : 0;
    const int colR = cgR ? (j0 + 4) : (W - 2);

    // Batched load: input rows base-2 .. base+9, 8 cols each -> 96 registers.
    // All 36 loads independent; compiler issues them back-to-back and drains
    // progressively as the selects consume them.
    float rows[NROWS][8];
#pragma unroll
    for (int t = 0; t < NROWS; ++t) {
        const int row   = base - PAD + t;
        const bool rok  = (row >= 0) && (row < H);
        const int  rowc = min(max(row, 0), H - 1);
        const float* rp = xp + rowc * W;
        const float2 L = *reinterpret_cast<const float2*>(rp + colL);
        const float4 M = *reinterpret_cast<const float4*>(rp + j0);
        const float2 R = *reinterpret_cast<const float2*>(rp + colR);
        rows[t][0] = (rok && cgL) ? L.x : 0.0f;
        rows[t][1] = (rok && cgL) ? L.y : 0.0f;
        rows[t][2] = rok ? M.x : 0.0f;
        rows[t][3] = rok ? M.y : 0.0f;
        rows[t][4] = rok ? M.z : 0.0f;
        rows[t][5] = rok ? M.w : 0.0f;
        rows[t][6] = (rok && cgR) ? R.x : 0.0f;
        rows[t][7] = (rok && cgR) ? R.y : 0.0f;
    }

    // Compute 8 output rows from registers; all indices compile-time.
#pragma unroll
    for (int it = 0; it < RSTRIP; ++it) {
        float res[4];
#pragma unroll
        for (int k = 0; k < 4; ++k) {
            float v[KH * KW];
#pragma unroll
            for (int r = 0; r < KH; ++r)
#pragma unroll
                for (int c = 0; c < KW; ++c)
                    v[r * KW + c] = rows[it + r][k + c] + wk[r * KW + c];

            const float u0 = MAX3(v[0],  v[1],  v[2]);
            const float u1 = MAX3(v[3],  v[4],  v[5]);
            const float u2 = MAX3(v[6],  v[7],  v[8]);
            const float u3 = MAX3(v[9],  v[10], v[11]);
            const float u4 = MAX3(v[12], v[13], v[14]);
            const float u5 = MAX3(v[15], v[16], v[17]);
            const float u6 = MAX3(v[18], v[19], v[20]);
            const float u7 = MAX3(v[21], v[22], v[23]);
            const float w0 = MAX3(u0, u1, u2);
            const float w1 = MAX3(u3, u4, u5);
            const float w2 = MAX3(u6, u7, v[24]);
            res[k] = MAX3(w0, w1, w2) + bi;
        }

        float4 o;
        o.x = res[0]; o.y = res[1]; o.z = res[2]; o.w = res[3];
        const int grow = base + it;
        *reinterpret_cast<float4*>(op + grow * W + j0) = o;
    }
}

extern "C" void kernel_launch(void* const* d_in, const int* in_sizes, int n_in,
                              void* d_out, int out_size, void* d_ws, size_t ws_size,
                              hipStream_t stream) {
    const float* x    = (const float*)d_in[0];
    const float* wgt  = (const float*)d_in[1];
    const float* bias = (const float*)d_in[2];
    float* out        = (float*)d_out;

    const int planes = in_sizes[2];          // B*C = 1024
    dim3 grid(planes * BANDS);               // 2048 blocks
    dim3 block(256);                         // 4 waves
    dilation_kernel<<<grid, block, 0, stream>>>(x, wgt, bias, out);
}

// Round 7
// 129.132 us; speedup vs baseline: 1.0125x; 1.0125x over previous
//
#include <hip/hip_runtime.h>

// Morphological dilation: out[p,i,j] = max_{r,c}(xpad[p,i+r,j+c] + w[p,r,c]) + bias[p]
// p = plane (B*C=1024), H=W=128, 5x5, pad=2, stride=1, fp32. Zero pad participates.
// R7 = R6 + __launch_bounds__(256, 3).  R6's VGPR_Count=40 proved the compiler
// sank the 36 batched loads back to their uses (max-occupancy register target),
// recreating the load->consume chains that plateau at ~40us. (256,3) grants a
// ~168-VGPR budget so the 96-float strip can stay live and all 36 loads issue
// up-front (ILP latency hiding), while 12 waves/CU keep TLP.

static constexpr int H = 128, W = 128, KH = 5, KW = 5, PAD = 2;
static constexpr int RSTRIP = 8;            // output rows per thread
static constexpr int NROWS  = RSTRIP + KH - 1; // 12 input rows held in regs
static constexpr int RBAND  = 64;           // output rows per block (8 strips)
static constexpr int BANDS  = H / RBAND;    // 2 blocks per plane

#define MAX3(a, b, c) fmaxf(fmaxf((a), (b)), (c))

__global__ __launch_bounds__(256, 3) void dilation_kernel(
    const float* __restrict__ x,
    const float* __restrict__ wgt,
    const float* __restrict__ bias,
    float* __restrict__ out)
{
    const int plane = blockIdx.x / BANDS;
    const int band  = blockIdx.x % BANDS;
    const int tid = threadIdx.x;
    const int cg  = tid & 31;     // column group: 4 cols each, 32 groups = 128 cols
    const int rs  = tid >> 5;     // row stream 0..7
    const int j0  = cg * 4;
    const int base = band * RBAND + rs * RSTRIP;

    const float* __restrict__ xp = x   + (size_t)plane * (H * W);
    float*       __restrict__ op = out + (size_t)plane * (H * W);
    const float* __restrict__ wp = wgt + plane * (KH * KW);

    // Plane-uniform weights -> SGPRs; bias applied last (exact ref op order).
    float wk[KH * KW];
#pragma unroll
    for (int i = 0; i < KH * KW; ++i) wk[i] = wp[i];
    const float bi = bias[plane];

    // Column-edge handling: window needs cols j0-2 .. j0+5 (8 floats).
    // L = float2 @ j0-2 (invalid for cg==0), M = float4 @ j0 (always valid),
    // R = float2 @ j0+4 (invalid for cg==31). Clamped addresses stay in-plane.
    const bool cgL = (cg > 0);
    const bool cgR = (cg < 31);
    const int colL = cgL ? (j0 - 2) : 0;
    const int colR = cgR ? (j0 + 4) : (W - 2);

    // Batched load: input rows base-2 .. base+9, 8 cols each -> 96 registers.
    // All 36 loads independent; with the (256,3) register budget the scheduler
    // can issue them back-to-back and drain progressively in the select phase.
    float rows[NROWS][8];
#pragma unroll
    for (int t = 0; t < NROWS; ++t) {
        const int row   = base - PAD + t;
        const bool rok  = (row >= 0) && (row < H);
        const int  rowc = min(max(row, 0), H - 1);
        const float* rp = xp + rowc * W;
        const float2 L = *reinterpret_cast<const float2*>(rp + colL);
        const float4 M = *reinterpret_cast<const float4*>(rp + j0);
        const float2 R = *reinterpret_cast<const float2*>(rp + colR);
        rows[t][0] = (rok && cgL) ? L.x : 0.0f;
        rows[t][1] = (rok && cgL) ? L.y : 0.0f;
        rows[t][2] = rok ? M.x : 0.0f;
        rows[t][3] = rok ? M.y : 0.0f;
        rows[t][4] = rok ? M.z : 0.0f;
        rows[t][5] = rok ? M.w : 0.0f;
        rows[t][6] = (rok && cgR) ? R.x : 0.0f;
        rows[t][7] = (rok && cgR) ? R.y : 0.0f;
    }

    // Compute 8 output rows from registers; all indices compile-time.
#pragma unroll
    for (int it = 0; it < RSTRIP; ++it) {
        float res[4];
#pragma unroll
        for (int k = 0; k < 4; ++k) {
            float v[KH * KW];
#pragma unroll
            for (int r = 0; r < KH; ++r)
#pragma unroll
                for (int c = 0; c < KW; ++c)
                    v[r * KW + c] = rows[it + r][k + c] + wk[r * KW + c];

            const float u0 = MAX3(v[0],  v[1],  v[2]);
            const float u1 = MAX3(v[3],  v[4],  v[5]);
            const float u2 = MAX3(v[6],  v[7],  v[8]);
            const float u3 = MAX3(v[9],  v[10], v[11]);
            const float u4 = MAX3(v[12], v[13], v[14]);
            const float u5 = MAX3(v[15], v[16], v[17]);
            const float u6 = MAX3(v[18], v[19], v[20]);
            const float u7 = MAX3(v[21], v[22], v[23]);
            const float w0 = MAX3(u0, u1, u2);
            const float w1 = MAX3(u3, u4, u5);
            const float w2 = MAX3(u6, u7, v[24]);
            res[k] = MAX3(w0, w1, w2) + bi;
        }

        float4 o;
        o.x = res[0]; o.y = res[1]; o.z = res[2]; o.w = res[3];
        const int grow = base + it;
        *reinterpret_cast<float4*>(op + grow * W + j0) = o;
    }
}

extern "C" void kernel_launch(void* const* d_in, const int* in_sizes, int n_in,
                              void* d_out, int out_size, void* d_ws, size_t ws_size,
                              hipStream_t stream) {
    const float* x    = (const float*)d_in[0];
    const float* wgt  = (const float*)d_in[1];
    const float* bias = (const float*)d_in[2];
    float* out        = (float*)d_out;

    const int planes = in_sizes[2];          // B*C = 1024
    dim3 grid(planes * BANDS);               // 2048 blocks
    dim3 block(256);                         // 4 waves
    dilation_kernel<<<grid, block, 0, stream>>>(x, wgt, bias, out);
}